// Round 9
// baseline (4523.266 us; speedup 1.0000x reference)
//
#include <hip/hip_runtime.h>
#include <hip/hip_cooperative_groups.h>

namespace cg = cooperative_groups;

typedef unsigned short u16;
typedef short short8 __attribute__((ext_vector_type(8)));
typedef float f32x4 __attribute__((ext_vector_type(4)));

// Problem constants
constexpr int B_  = 2;
constexpr int T_  = 256;
constexpr int V_  = 512;
constexpr int E_  = 768;
constexpr int L_  = 12;
constexpr int NH_ = 12;
constexpr int HD_ = 64;
constexpr int E3_ = 3 * E_;       // 2304
constexpr int E4_ = 4 * E_;       // 3072
constexpr int CPD_ = 2048;        // H_CP*V*R
constexpr int NTOK_ = B_ * T_;    // 512
constexpr int NVALID_ = B_ * (T_ - 2); // 508
constexpr size_t PS_ = (size_t)NTOK_ * E_;    // ao/mo partial stride (floats)
constexpr size_t QS_ = (size_t)NTOK_ * E3_;   // qkv partial stride
constexpr size_t FS_ = (size_t)NTOK_ * E4_;   // fc partial stride
constexpr size_t CS_ = (size_t)NTOK_ * CPD_;  // cp partial stride

__device__ __forceinline__ u16 f2b(float f) {  // RNE f32 -> bf16 bits
    union { float f; unsigned int u; } c; c.f = f;
    unsigned int r = (c.u + 0x7FFFu + ((c.u >> 16) & 1u)) >> 16; return (u16)r;
}

// ======================================================================
// ===============  FALLBACK KERNELS (exact R8, 1321 us)  ===============
// ======================================================================

__global__ __launch_bounds__(256) void ln_res_k(float* __restrict__ h,
    const float* __restrict__ pb, int np,
    const int* __restrict__ ids, const float* __restrict__ wte,
    const float* __restrict__ wpe,
    const float* __restrict__ g, const float* __restrict__ bta,
    u16* __restrict__ out) {
    int n = blockIdx.x;
    int tid = threadIdx.x;
    size_t off = (size_t)n * E_;
    float v0, v1, v2;
    if (np < 0) {
        int t = n % T_;
        int tok = ids[n];
        size_t wo = (size_t)tok * E_, po = (size_t)t * E_;
        v0 = wte[wo + tid]       + wpe[po + tid];
        v1 = wte[wo + tid + 256] + wpe[po + tid + 256];
        v2 = wte[wo + tid + 512] + wpe[po + tid + 512];
        h[off + tid] = v0; h[off + tid + 256] = v1; h[off + tid + 512] = v2;
    } else {
        v0 = h[off + tid]; v1 = h[off + tid + 256]; v2 = h[off + tid + 512];
        for (int j = 0; j < np; j++) {
            const float* p = pb + (size_t)j * PS_ + off;
            v0 += p[tid]; v1 += p[tid + 256]; v2 += p[tid + 512];
        }
        if (np) { h[off + tid] = v0; h[off + tid + 256] = v1; h[off + tid + 512] = v2; }
    }
    __shared__ float red[256];
    red[tid] = v0 + v1 + v2;
    __syncthreads();
    for (int o = 128; o > 0; o >>= 1) { if (tid < o) red[tid] += red[tid + o]; __syncthreads(); }
    float mean = red[0] * (1.0f / E_);
    __syncthreads();
    float d0 = v0 - mean, d1 = v1 - mean, d2 = v2 - mean;
    red[tid] = d0 * d0 + d1 * d1 + d2 * d2;
    __syncthreads();
    for (int o = 128; o > 0; o >>= 1) { if (tid < o) red[tid] += red[tid + o]; __syncthreads(); }
    float rstd = rsqrtf(red[0] * (1.0f / E_) + 1e-5f);
    u16* y = out + off;
    y[tid]       = f2b(d0 * rstd * g[tid]       + bta[tid]);
    y[tid + 256] = f2b(d1 * rstd * g[tid + 256] + bta[tid + 256]);
    y[tid + 512] = f2b(d2 * rstd * g[tid + 512] + bta[tid + 512]);
}

__global__ __launch_bounds__(512) void mgemm_k(const u16* __restrict__ A,
    const float* __restrict__ W, const float* __restrict__ bias,
    float* __restrict__ outP, int K, int KC, int N) {
    __shared__ u16 As[128 * 40];
    __shared__ u16 Bs[128 * 40];
    int tid = threadIdx.x, lane = tid & 63, wid = tid >> 6;
    int ln15 = lane & 15, quad = lane >> 4;
    int col0 = blockIdx.x * 128, row0 = blockIdx.y * 128;
    int kz = blockIdx.z, kbase = kz * KC;
    int ar = tid >> 2, ak = (tid & 3) * 8;
    const u16* Ag = A + (size_t)(row0 + ar) * K + kbase + ak;
    u16* Aw = &As[ar * 40 + ak];
    int bc = tid & 127, kg = (tid >> 7) * 8;
    const float* Wg = W + (size_t)(kbase + kg) * N + col0 + bc;
    u16* Bw = &Bs[bc * 40 + kg];
    int wr = (wid & 3) * 32, wc = (wid >> 2) * 64;

    f32x4 acc[2][4];
#pragma unroll
    for (int mt = 0; mt < 2; mt++)
#pragma unroll
        for (int nt = 0; nt < 4; nt++) acc[mt][nt] = (f32x4){0.f, 0.f, 0.f, 0.f};

    uint4 av = *(const uint4*)Ag;
    float w[8];
#pragma unroll
    for (int i = 0; i < 8; i++) w[i] = Wg[(size_t)i * N];

    for (int k0 = 0; k0 < KC; k0 += 32) {
        uint4 avn = av;
        float wn[8];
#pragma unroll
        for (int i = 0; i < 8; i++) wn[i] = w[i];
        if (k0 + 32 < KC) {
            avn = *(const uint4*)(Ag + k0 + 32);
#pragma unroll
            for (int i = 0; i < 8; i++) wn[i] = Wg[(size_t)(k0 + 32 + i) * N];
        }
        uint4 bv;
        asm("v_cvt_pk_bf16_f32 %0, %1, %2" : "=v"(bv.x) : "v"(w[0]), "v"(w[1]));
        asm("v_cvt_pk_bf16_f32 %0, %1, %2" : "=v"(bv.y) : "v"(w[2]), "v"(w[3]));
        asm("v_cvt_pk_bf16_f32 %0, %1, %2" : "=v"(bv.z) : "v"(w[4]), "v"(w[5]));
        asm("v_cvt_pk_bf16_f32 %0, %1, %2" : "=v"(bv.w) : "v"(w[6]), "v"(w[7]));
        __syncthreads();
        *(uint4*)Aw = av;
        *(uint4*)Bw = bv;
        __syncthreads();
        short8 af[2], bf[4];
#pragma unroll
        for (int mt = 0; mt < 2; mt++)
            af[mt] = *(const short8*)&As[(wr + mt * 16 + ln15) * 40 + quad * 8];
#pragma unroll
        for (int nt = 0; nt < 4; nt++)
            bf[nt] = *(const short8*)&Bs[(wc + nt * 16 + ln15) * 40 + quad * 8];
#pragma unroll
        for (int mt = 0; mt < 2; mt++)
#pragma unroll
            for (int nt = 0; nt < 4; nt++)
                acc[mt][nt] = __builtin_amdgcn_mfma_f32_16x16x32_bf16(
                    af[mt], bf[nt], acc[mt][nt], 0, 0, 0);
        av = avn;
#pragma unroll
        for (int i = 0; i < 8; i++) w[i] = wn[i];
    }
    float* dst = outP + (size_t)kz * NTOK_ * N;
#pragma unroll
    for (int mt = 0; mt < 2; mt++) {
#pragma unroll
        for (int nt = 0; nt < 4; nt++) {
            int c = col0 + wc + nt * 16 + ln15;
            float bb = (kz == 0) ? bias[c] : 0.f;
#pragma unroll
            for (int r = 0; r < 4; r++) {
                int rw = row0 + wr + mt * 16 + quad * 4 + r;
                dst[(size_t)rw * N + c] = acc[mt][nt][r] + bb;
            }
        }
    }
}

__global__ __launch_bounds__(256) void gelu_k(const float* __restrict__ p0,
    const float* __restrict__ p1, u16* __restrict__ out) {
    size_t i = ((size_t)blockIdx.x * 256 + threadIdx.x) * 4;
    float4 a = *(const float4*)&p0[i];
    float4 b = *(const float4*)&p1[i];
    float u[4] = {a.x + b.x, a.y + b.y, a.z + b.z, a.w + b.w};
    ushort4 o;
    u16* op = (u16*)&o;
#pragma unroll
    for (int j = 0; j < 4; j++) {
        float uu = u[j];
        float inner = 0.7978845608028654f * (uu + 0.044715f * uu * uu * uu);
        op[j] = f2b(0.5f * uu * (1.0f + tanhf(inner)));
    }
    *(ushort4*)&out[i] = o;
}

constexpr int KSTR_ = 72;
constexpr int PSTR_ = 264;
__global__ __launch_bounds__(256) void fattn_k(const float* __restrict__ qp,
    u16* __restrict__ o) {
    __shared__ u16 Ks[256 * KSTR_];
    __shared__ u16 Vt[64 * PSTR_];
    __shared__ u16 Ps[64 * PSTR_];
    int qt = blockIdx.x;
    int bh = blockIdx.y;
    int hh = bh % NH_, b = bh / NH_;
    int tid = threadIdx.x, lane = tid & 63, wid = tid >> 6;
    int ln15 = lane & 15, quad = lane >> 4;

    int sr = tid >> 4, sd = (tid & 15) * 4;
#pragma unroll
    for (int pass = 0; pass < 16; pass++) {
        int rr = sr + pass * 16;
        size_t rowbase = (size_t)(b * T_ + rr) * E3_ + hh * HD_ + sd;
        float kx = 0.f, ky = 0.f, kz = 0.f, kw = 0.f;
        float vx = 0.f, vy = 0.f, vz = 0.f, vw = 0.f;
#pragma unroll
        for (int pi = 0; pi < 4; pi++) {
            float4 kk = *(const float4*)&qp[pi * QS_ + rowbase + E_];
            float4 vv = *(const float4*)&qp[pi * QS_ + rowbase + 2 * E_];
            kx += kk.x; ky += kk.y; kz += kk.z; kw += kk.w;
            vx += vv.x; vy += vv.y; vz += vv.z; vw += vv.w;
        }
        uint2 pk;
        asm("v_cvt_pk_bf16_f32 %0, %1, %2" : "=v"(pk.x) : "v"(kx), "v"(ky));
        asm("v_cvt_pk_bf16_f32 %0, %1, %2" : "=v"(pk.y) : "v"(kz), "v"(kw));
        *(uint2*)&Ks[rr * KSTR_ + sd] = pk;
        Vt[(sd + 0) * PSTR_ + rr] = f2b(vx);
        Vt[(sd + 1) * PSTR_ + rr] = f2b(vy);
        Vt[(sd + 2) * PSTR_ + rr] = f2b(vz);
        Vt[(sd + 3) * PSTR_ + rr] = f2b(vw);
    }

    size_t qbase = (size_t)(b * T_ + qt * 64 + wid * 16 + ln15) * E3_ + hh * HD_;
    short8 qf[2];
#pragma unroll
    for (int ks = 0; ks < 2; ks++) {
        float s8[8] = {0.f, 0.f, 0.f, 0.f, 0.f, 0.f, 0.f, 0.f};
#pragma unroll
        for (int pi = 0; pi < 4; pi++) {
            const float* src = &qp[pi * QS_ + qbase + ks * 32 + quad * 8];
            float4 a = *(const float4*)src;
            float4 b4 = *(const float4*)(src + 4);
            s8[0] += a.x; s8[1] += a.y; s8[2] += a.z; s8[3] += a.w;
            s8[4] += b4.x; s8[5] += b4.y; s8[6] += b4.z; s8[7] += b4.w;
        }
        union { short8 s; unsigned int u[4]; } uq;
#pragma unroll
        for (int i = 0; i < 4; i++)
            asm("v_cvt_pk_bf16_f32 %0, %1, %2" : "=v"(uq.u[i]) : "v"(s8[2 * i]), "v"(s8[2 * i + 1]));
        qf[ks] = uq.s;
    }

    __syncthreads();

    f32x4 s[16];
#pragma unroll
    for (int nt = 0; nt < 16; nt++) s[nt] = (f32x4){0.f, 0.f, 0.f, 0.f};
#pragma unroll
    for (int ks = 0; ks < 2; ks++) {
#pragma unroll
        for (int nt = 0; nt < 16; nt++) {
            short8 kf = *(const short8*)&Ks[(nt * 16 + ln15) * KSTR_ + ks * 32 + quad * 8];
            s[nt] = __builtin_amdgcn_mfma_f32_16x16x32_bf16(qf[ks], kf, s[nt], 0, 0, 0);
        }
    }

#pragma unroll
    for (int r = 0; r < 4; r++) {
        int q = qt * 64 + wid * 16 + quad * 4 + r;
        float m = -1e30f;
#pragma unroll
        for (int nt = 0; nt < 16; nt++) {
            int j = nt * 16 + ln15;
            float sv = (j <= q) ? s[nt][r] * 0.125f : -1e9f;
            s[nt][r] = sv;
            m = fmaxf(m, sv);
        }
        m = fmaxf(m, __shfl_xor(m, 1));
        m = fmaxf(m, __shfl_xor(m, 2));
        m = fmaxf(m, __shfl_xor(m, 4));
        m = fmaxf(m, __shfl_xor(m, 8));
        float sum = 0.f;
#pragma unroll
        for (int nt = 0; nt < 16; nt++) {
            float p = __expf(s[nt][r] - m);
            s[nt][r] = p;
            sum += p;
        }
        sum += __shfl_xor(sum, 1);
        sum += __shfl_xor(sum, 2);
        sum += __shfl_xor(sum, 4);
        sum += __shfl_xor(sum, 8);
        float inv = 1.0f / sum;
#pragma unroll
        for (int nt = 0; nt < 16; nt++) s[nt][r] *= inv;
    }

#pragma unroll
    for (int nt = 0; nt < 16; nt++)
#pragma unroll
        for (int r = 0; r < 4; r++)
            Ps[(wid * 16 + quad * 4 + r) * PSTR_ + nt * 16 + ln15] = f2b(s[nt][r]);

    __syncthreads();

    f32x4 oacc[4];
#pragma unroll
    for (int dt = 0; dt < 4; dt++) oacc[dt] = (f32x4){0.f, 0.f, 0.f, 0.f};
#pragma unroll
    for (int ks = 0; ks < 8; ks++) {
        short8 pf = *(const short8*)&Ps[(wid * 16 + ln15) * PSTR_ + ks * 32 + quad * 8];
#pragma unroll
        for (int dt = 0; dt < 4; dt++) {
            short8 vf = *(const short8*)&Vt[(dt * 16 + ln15) * PSTR_ + ks * 32 + quad * 8];
            oacc[dt] = __builtin_amdgcn_mfma_f32_16x16x32_bf16(pf, vf, oacc[dt], 0, 0, 0);
        }
    }

#pragma unroll
    for (int dt = 0; dt < 4; dt++) {
#pragma unroll
        for (int r = 0; r < 4; r++) {
            int q = qt * 64 + wid * 16 + quad * 4 + r;
            o[(size_t)(b * T_ + q) * E_ + hh * HD_ + dt * 16 + ln15] = f2b(oacc[dt][r]);
        }
    }
}

__global__ __launch_bounds__(256) void zloss_k(const float* __restrict__ cp,
    const int* __restrict__ ids, float* __restrict__ lossv) {
    int n = blockIdx.x;
    int b = n / (T_ - 2), t = n % (T_ - 2);
    int nf = b * T_ + t;
    size_t base = (size_t)nf * CPD_;
    __shared__ float A0[V_], A1[V_], B0[V_], B1[V_];
    __shared__ float red[256];
    int tid = threadIdx.x;
    for (int v = tid; v < V_; v += 256) {
        float a0 = 0.f, a1 = 0.f, b0 = 0.f, b1 = 0.f;
#pragma unroll
        for (int pi = 0; pi < 4; pi++) {
            const float* ap = cp + pi * CS_ + base;
            float2 av = *(const float2*)&ap[2 * v];
            float2 bv = *(const float2*)&ap[1024 + 2 * v];
            a0 += av.x; a1 += av.y; b0 += bv.x; b1 += bv.y;
        }
        A0[v] = a0; A1[v] = a1; B0[v] = b0; B1[v] = b1;
    }
    __syncthreads();
    float acc = 0.f;
    for (int j = tid; j < V_; j += 256) {
        float b0 = B0[j], b1 = B1[j];
        for (int i = 0; i < V_; i++)
            acc += __expf(A0[i] * b0 + A1[i] * b1);
    }
    red[tid] = acc; __syncthreads();
    for (int off = 128; off > 0; off >>= 1) { if (tid < off) red[tid] += red[tid + off]; __syncthreads(); }
    if (tid == 0) {
        int t0 = ids[b * T_ + t + 1];
        int t1 = ids[b * T_ + t + 2];
        float score = A0[t0] * B0[t1] + A1[t0] * B1[t1];
        lossv[n] = logf(red[0]) - score;
    }
}

__global__ __launch_bounds__(256) void reduce_k(const float* __restrict__ lossv,
    unsigned int* __restrict__ out) {
    __shared__ float red[256];
    int tid = threadIdx.x;
    float s = 0.f;
    for (int i = tid; i < NVALID_; i += 256) s += lossv[i];
    red[tid] = s; __syncthreads();
    for (int off = 128; off > 0; off >>= 1) { if (tid < off) red[tid] += red[tid + off]; __syncthreads(); }
    if (tid == 0) {
        float loss = red[0] / (float)NVALID_;
        union { float f; unsigned int u; } cv; cv.f = loss;
        unsigned int b = (cv.u + 0x7FFFu + ((cv.u >> 16) & 1u)) >> 16;
        out[0] = (b << 16) | b;
    }
}

// ======================================================================
// ==================  COOPERATIVE MEGAKERNEL PATH  =====================
// ======================================================================
// 256 blocks x 512 threads, 1 block/CU (69 KB LDS), grid.sync between stages.
// Per-element arithmetic identical to the R8 kernels above.

struct MKP {
    const int* ids; const float* wte; const float* wpe;
    const float* ln1g; const float* ln1b; const float* ln2g; const float* ln2b;
    const float* wqkv; const float* bqkv; const float* wao; const float* bao;
    const float* wfc; const float* bfc; const float* wmo; const float* bmo;
    const float* lnfg; const float* lnfb; const float* wcp; const float* bcp;
    float* h; u16* x; u16* aob; u16* fcb; float* pbuf; float* lossv;
    unsigned int* out;
};

// ---- LN unit: exact R8 arithmetic on threads 0-255; barriers all-thread ----
__device__ void mk_ln_unit(int n, float* h, const float* pb, int np,
    const int* ids, const float* wte, const float* wpe,
    const float* g, const float* bta, u16* out, float* red) {
    int tid = threadIdx.x;
    size_t off = (size_t)n * E_;
    float v0 = 0.f, v1 = 0.f, v2 = 0.f;
    if (tid < 256) {
        if (np < 0) {
            int t = n % T_;
            int tok = ids[n];
            size_t wo = (size_t)tok * E_, po = (size_t)t * E_;
            v0 = wte[wo + tid]       + wpe[po + tid];
            v1 = wte[wo + tid + 256] + wpe[po + tid + 256];
            v2 = wte[wo + tid + 512] + wpe[po + tid + 512];
            h[off + tid] = v0; h[off + tid + 256] = v1; h[off + tid + 512] = v2;
        } else {
            v0 = h[off + tid]; v1 = h[off + tid + 256]; v2 = h[off + tid + 512];
            for (int j = 0; j < np; j++) {
                const float* p = pb + (size_t)j * PS_ + off;
                v0 += p[tid]; v1 += p[tid + 256]; v2 += p[tid + 512];
            }
            if (np) { h[off + tid] = v0; h[off + tid + 256] = v1; h[off + tid + 512] = v2; }
        }
        red[tid] = v0 + v1 + v2;
    }
    __syncthreads();
    for (int o = 128; o > 0; o >>= 1) { if (tid < o) red[tid] += red[tid + o]; __syncthreads(); }
    float mean = red[0] * (1.0f / E_);
    __syncthreads();
    float d0 = v0 - mean, d1 = v1 - mean, d2 = v2 - mean;
    if (tid < 256) red[tid] = d0 * d0 + d1 * d1 + d2 * d2;
    __syncthreads();
    for (int o = 128; o > 0; o >>= 1) { if (tid < o) red[tid] += red[tid + o]; __syncthreads(); }
    float rstd = rsqrtf(red[0] * (1.0f / E_) + 1e-5f);
    if (tid < 256) {
        u16* y = out + off;
        y[tid]       = f2b(d0 * rstd * g[tid]       + bta[tid]);
        y[tid + 256] = f2b(d1 * rstd * g[tid + 256] + bta[tid + 256]);
        y[tid + 512] = f2b(d2 * rstd * g[tid + 512] + bta[tid + 512]);
    }
    __syncthreads();
}

// ---- GEMM tiles: exact R8 tile body over flattened tile index ----
__device__ void mk_gemm(const u16* __restrict__ A, const float* __restrict__ W,
    const float* __restrict__ bias, float* __restrict__ outP,
    int K, int KC, int N, int ntiles, int nx, u16* As, u16* Bs) {
    int tid = threadIdx.x, lane = tid & 63, wid = tid >> 6;
    int ln15 = lane & 15, quad = lane >> 4;
    int ar = tid >> 2, ak = (tid & 3) * 8;
    int bc = tid & 127, kg = (tid >> 7) * 8;
    int wr = (wid & 3) * 32, wc = (wid >> 2) * 64;
    for (int t = blockIdx.x; t < ntiles; t += 256) {
        int bx = t % nx, by = (t / nx) & 3, kz = t / (nx * 4);
        int col0 = bx * 128, row0 = by * 128, kbase = kz * KC;
        const u16* Ag = A + (size_t)(row0 + ar) * K + kbase + ak;
        u16* Aw = &As[ar * 40 + ak];
        const float* Wg = W + (size_t)(kbase + kg) * N + col0 + bc;
        u16* Bw = &Bs[bc * 40 + kg];

        f32x4 acc[2][4];
#pragma unroll
        for (int mt = 0; mt < 2; mt++)
#pragma unroll
            for (int nt = 0; nt < 4; nt++) acc[mt][nt] = (f32x4){0.f, 0.f, 0.f, 0.f};

        uint4 av = *(const uint4*)Ag;
        float w[8];
#pragma unroll
        for (int i = 0; i < 8; i++) w[i] = Wg[(size_t)i * N];

        for (int k0 = 0; k0 < KC; k0 += 32) {
            uint4 avn = av;
            float wn[8];
#pragma unroll
            for (int i = 0; i < 8; i++) wn[i] = w[i];
            if (k0 + 32 < KC) {
                avn = *(const uint4*)(Ag + k0 + 32);
#pragma unroll
                for (int i = 0; i < 8; i++) wn[i] = Wg[(size_t)(k0 + 32 + i) * N];
            }
            uint4 bv;
            asm("v_cvt_pk_bf16_f32 %0, %1, %2" : "=v"(bv.x) : "v"(w[0]), "v"(w[1]));
            asm("v_cvt_pk_bf16_f32 %0, %1, %2" : "=v"(bv.y) : "v"(w[2]), "v"(w[3]));
            asm("v_cvt_pk_bf16_f32 %0, %1, %2" : "=v"(bv.z) : "v"(w[4]), "v"(w[5]));
            asm("v_cvt_pk_bf16_f32 %0, %1, %2" : "=v"(bv.w) : "v"(w[6]), "v"(w[7]));
            __syncthreads();
            *(uint4*)Aw = av;
            *(uint4*)Bw = bv;
            __syncthreads();
            short8 af[2], bf[4];
#pragma unroll
            for (int mt = 0; mt < 2; mt++)
                af[mt] = *(const short8*)&As[(wr + mt * 16 + ln15) * 40 + quad * 8];
#pragma unroll
            for (int nt = 0; nt < 4; nt++)
                bf[nt] = *(const short8*)&Bs[(wc + nt * 16 + ln15) * 40 + quad * 8];
#pragma unroll
            for (int mt = 0; mt < 2; mt++)
#pragma unroll
                for (int nt = 0; nt < 4; nt++)
                    acc[mt][nt] = __builtin_amdgcn_mfma_f32_16x16x32_bf16(
                        af[mt], bf[nt], acc[mt][nt], 0, 0, 0);
            av = avn;
#pragma unroll
            for (int i = 0; i < 8; i++) w[i] = wn[i];
        }
        float* dst = outP + (size_t)kz * NTOK_ * N;
#pragma unroll
        for (int mt = 0; mt < 2; mt++) {
#pragma unroll
            for (int nt = 0; nt < 4; nt++) {
                int c = col0 + wc + nt * 16 + ln15;
                float bb = (kz == 0) ? bias[c] : 0.f;
#pragma unroll
                for (int r = 0; r < 4; r++) {
                    int rw = row0 + wr + mt * 16 + quad * 4 + r;
                    dst[(size_t)rw * N + c] = acc[mt][nt][r] + bb;
                }
            }
        }
        __syncthreads();   // protect As/Bs before next tile's writes
    }
}

// ---- attention unit: staging on 512 threads (elementwise-identical), compute on 256 ----
// Ps aliases Ks (dead after QK^T) -> 69 KB LDS total.
__device__ void mk_attn_unit(const float* __restrict__ qp, u16* __restrict__ o,
    int unit, u16* Ks, u16* Vt, u16* Ps) {
    int qt = unit % 4, bh = unit / 4;
    int hh = bh % NH_, b = bh / NH_;
    int tid = threadIdx.x, lane = tid & 63, wid = tid >> 6;
    int ln15 = lane & 15, quad = lane >> 4;

    int sr = tid >> 4, sd = (tid & 15) * 4;      // sr in [0,32) with 512 threads
#pragma unroll
    for (int pass = 0; pass < 8; pass++) {
        int rr = sr + pass * 32;
        size_t rowbase = (size_t)(b * T_ + rr) * E3_ + hh * HD_ + sd;
        float kx = 0.f, ky = 0.f, kz = 0.f, kw = 0.f;
        float vx = 0.f, vy = 0.f, vz = 0.f, vw = 0.f;
#pragma unroll
        for (int pi = 0; pi < 4; pi++) {
            float4 kk = *(const float4*)&qp[pi * QS_ + rowbase + E_];
            float4 vv = *(const float4*)&qp[pi * QS_ + rowbase + 2 * E_];
            kx += kk.x; ky += kk.y; kz += kk.z; kw += kk.w;
            vx += vv.x; vy += vv.y; vz += vv.z; vw += vv.w;
        }
        uint2 pk;
        asm("v_cvt_pk_bf16_f32 %0, %1, %2" : "=v"(pk.x) : "v"(kx), "v"(ky));
        asm("v_cvt_pk_bf16_f32 %0, %1, %2" : "=v"(pk.y) : "v"(kz), "v"(kw));
        *(uint2*)&Ks[rr * KSTR_ + sd] = pk;
        Vt[(sd + 0) * PSTR_ + rr] = f2b(vx);
        Vt[(sd + 1) * PSTR_ + rr] = f2b(vy);
        Vt[(sd + 2) * PSTR_ + rr] = f2b(vz);
        Vt[(sd + 3) * PSTR_ + rr] = f2b(vw);
    }

    short8 qf[2];
    f32x4 s[16];
    if (tid < 256) {
        size_t qbase = (size_t)(b * T_ + qt * 64 + wid * 16 + ln15) * E3_ + hh * HD_;
#pragma unroll
        for (int ks = 0; ks < 2; ks++) {
            float s8[8] = {0.f, 0.f, 0.f, 0.f, 0.f, 0.f, 0.f, 0.f};
#pragma unroll
            for (int pi = 0; pi < 4; pi++) {
                const float* src = &qp[pi * QS_ + qbase + ks * 32 + quad * 8];
                float4 a = *(const float4*)src;
                float4 b4 = *(const float4*)(src + 4);
                s8[0] += a.x; s8[1] += a.y; s8[2] += a.z; s8[3] += a.w;
                s8[4] += b4.x; s8[5] += b4.y; s8[6] += b4.z; s8[7] += b4.w;
            }
            union { short8 s; unsigned int u[4]; } uq;
#pragma unroll
            for (int i = 0; i < 4; i++)
                asm("v_cvt_pk_bf16_f32 %0, %1, %2" : "=v"(uq.u[i]) : "v"(s8[2 * i]), "v"(s8[2 * i + 1]));
            qf[ks] = uq.s;
        }
    }

    __syncthreads();   // staging complete

    if (tid < 256) {
#pragma unroll
        for (int nt = 0; nt < 16; nt++) s[nt] = (f32x4){0.f, 0.f, 0.f, 0.f};
#pragma unroll
        for (int ks = 0; ks < 2; ks++) {
#pragma unroll
            for (int nt = 0; nt < 16; nt++) {
                short8 kf = *(const short8*)&Ks[(nt * 16 + ln15) * KSTR_ + ks * 32 + quad * 8];
                s[nt] = __builtin_amdgcn_mfma_f32_16x16x32_bf16(qf[ks], kf, s[nt], 0, 0, 0);
            }
        }
#pragma unroll
        for (int r = 0; r < 4; r++) {
            int q = qt * 64 + wid * 16 + quad * 4 + r;
            float m = -1e30f;
#pragma unroll
            for (int nt = 0; nt < 16; nt++) {
                int j = nt * 16 + ln15;
                float sv = (j <= q) ? s[nt][r] * 0.125f : -1e9f;
                s[nt][r] = sv;
                m = fmaxf(m, sv);
            }
            m = fmaxf(m, __shfl_xor(m, 1));
            m = fmaxf(m, __shfl_xor(m, 2));
            m = fmaxf(m, __shfl_xor(m, 4));
            m = fmaxf(m, __shfl_xor(m, 8));
            float sum = 0.f;
#pragma unroll
            for (int nt = 0; nt < 16; nt++) {
                float p = __expf(s[nt][r] - m);
                s[nt][r] = p;
                sum += p;
            }
            sum += __shfl_xor(sum, 1);
            sum += __shfl_xor(sum, 2);
            sum += __shfl_xor(sum, 4);
            sum += __shfl_xor(sum, 8);
            float inv = 1.0f / sum;
#pragma unroll
            for (int nt = 0; nt < 16; nt++) s[nt][r] *= inv;
        }
    }

    __syncthreads();   // all Ks reads complete (Ps aliases Ks)

    if (tid < 256) {
#pragma unroll
        for (int nt = 0; nt < 16; nt++)
#pragma unroll
            for (int r = 0; r < 4; r++)
                Ps[(wid * 16 + quad * 4 + r) * PSTR_ + nt * 16 + ln15] = f2b(s[nt][r]);
    }

    __syncthreads();   // Ps ready

    if (tid < 256) {
        f32x4 oacc[4];
#pragma unroll
        for (int dt = 0; dt < 4; dt++) oacc[dt] = (f32x4){0.f, 0.f, 0.f, 0.f};
#pragma unroll
        for (int ks = 0; ks < 8; ks++) {
            short8 pf = *(const short8*)&Ps[(wid * 16 + ln15) * PSTR_ + ks * 32 + quad * 8];
#pragma unroll
            for (int dt = 0; dt < 4; dt++) {
                short8 vf = *(const short8*)&Vt[(dt * 16 + ln15) * PSTR_ + ks * 32 + quad * 8];
                oacc[dt] = __builtin_amdgcn_mfma_f32_16x16x32_bf16(pf, vf, oacc[dt], 0, 0, 0);
            }
        }
#pragma unroll
        for (int dt = 0; dt < 4; dt++) {
#pragma unroll
            for (int r = 0; r < 4; r++) {
                int q = qt * 64 + wid * 16 + quad * 4 + r;
                o[(size_t)(b * T_ + q) * E_ + hh * HD_ + dt * 16 + ln15] = f2b(oacc[dt][r]);
            }
        }
    }
}

// ---- zloss unit: exact R8 arithmetic on threads 0-255 ----
__device__ void mk_zloss_unit(const float* cp, const int* ids, float* lossv, int n,
    float* A0, float* A1, float* B0, float* B1, float* red) {
    int b = n / (T_ - 2), t = n % (T_ - 2);
    int nf = b * T_ + t;
    size_t base = (size_t)nf * CPD_;
    int tid = threadIdx.x;
    if (tid < 256) {
        for (int v = tid; v < V_; v += 256) {
            float a0 = 0.f, a1 = 0.f, b0 = 0.f, b1 = 0.f;
#pragma unroll
            for (int pi = 0; pi < 4; pi++) {
                const float* ap = cp + pi * CS_ + base;
                float2 av = *(const float2*)&ap[2 * v];
                float2 bv = *(const float2*)&ap[1024 + 2 * v];
                a0 += av.x; a1 += av.y; b0 += bv.x; b1 += bv.y;
            }
            A0[v] = a0; A1[v] = a1; B0[v] = b0; B1[v] = b1;
        }
    }
    __syncthreads();
    float acc = 0.f;
    if (tid < 256) {
        for (int j = tid; j < V_; j += 256) {
            float b0 = B0[j], b1 = B1[j];
            for (int i = 0; i < V_; i++)
                acc += __expf(A0[i] * b0 + A1[i] * b1);
        }
        red[tid] = acc;
    }
    __syncthreads();
    for (int off = 128; off > 0; off >>= 1) { if (tid < off) red[tid] += red[tid + off]; __syncthreads(); }
    if (tid == 0) {
        int t0 = ids[b * T_ + t + 1];
        int t1 = ids[b * T_ + t + 2];
        float score = A0[t0] * B0[t1] + A1[t0] * B1[t1];
        lossv[n] = logf(red[0]) - score;
    }
    __syncthreads();
}

__device__ void mk_reduce(const float* lossv, unsigned int* out, float* red) {
    int tid = threadIdx.x;
    if (tid < 256) {
        float s = 0.f;
        for (int i = tid; i < NVALID_; i += 256) s += lossv[i];
        red[tid] = s;
    }
    __syncthreads();
    for (int off = 128; off > 0; off >>= 1) { if (tid < off) red[tid] += red[tid + off]; __syncthreads(); }
    if (tid == 0) {
        float loss = red[0] / (float)NVALID_;
        union { float f; unsigned int u; } cv; cv.f = loss;
        unsigned int b = (cv.u + 0x7FFFu + ((cv.u >> 16) & 1u)) >> 16;
        out[0] = (b << 16) | b;
    }
}

__global__ __launch_bounds__(512, 2) void mega_k(MKP p) {
    cg::grid_group grid = cg::this_grid();
    __shared__ __align__(16) unsigned char smem[70656];
    u16* As = (u16*)smem;
    u16* Bs = (u16*)(smem + 10240);
    u16* Ks = (u16*)smem;                 // 36864 B
    u16* Vt = (u16*)(smem + 36864);       // 33792 B
    u16* Ps = Ks;                         // aliases Ks (dead after QK^T)
    float* red = (float*)smem;
    float* zA0 = (float*)smem;
    float* zA1 = zA0 + 512;
    float* zB0 = zA0 + 1024;
    float* zB1 = zA0 + 1536;
    float* zred = zA0 + 2048;
    int blk = blockIdx.x;

    for (int l = 0; l < L_; l++) {
        for (int u = blk; u < NTOK_; u += 256)
            mk_ln_unit(u, p.h, p.pbuf, l ? 8 : -1, p.ids, p.wte, p.wpe,
                       p.ln1g + l * E_, p.ln1b + l * E_, p.x, red);
        grid.sync();
        mk_gemm(p.x, p.wqkv + (size_t)l * E_ * E3_, p.bqkv + l * E3_, p.pbuf,
                E_, 192, E3_, 288, 18, As, Bs);
        grid.sync();
        if (blk < 96) mk_attn_unit(p.pbuf, p.aob, blk, Ks, Vt, Ps);
        grid.sync();
        mk_gemm(p.aob, p.wao + (size_t)l * E_ * E_, p.bao + l * E_, p.pbuf,
                E_, 96, E_, 192, 6, As, Bs);
        grid.sync();
        for (int u = blk; u < NTOK_; u += 256)
            mk_ln_unit(u, p.h, p.pbuf, 8, p.ids, p.wte, p.wpe,
                       p.ln2g + l * E_, p.ln2b + l * E_, p.x, red);
        grid.sync();
        mk_gemm(p.x, p.wfc + (size_t)l * E_ * E4_, p.bfc + l * E4_, p.pbuf,
                E_, 384, E4_, 192, 24, As, Bs);
        grid.sync();
        {   // gelu over 2 fc partials -> bf16 (elementwise, identical math)
            const float* p0 = p.pbuf;
            const float* p1 = p.pbuf + FS_;
            size_t nitems = (size_t)NTOK_ * E4_ / 4;
            for (size_t it = (size_t)blk * 512 + threadIdx.x; it < nitems; it += (size_t)256 * 512) {
                size_t i = it * 4;
                float4 a = *(const float4*)&p0[i];
                float4 b = *(const float4*)&p1[i];
                float u4[4] = {a.x + b.x, a.y + b.y, a.z + b.z, a.w + b.w};
                ushort4 o;
                u16* op = (u16*)&o;
#pragma unroll
                for (int j = 0; j < 4; j++) {
                    float uu = u4[j];
                    float inner = 0.7978845608028654f * (uu + 0.044715f * uu * uu * uu);
                    op[j] = f2b(0.5f * uu * (1.0f + tanhf(inner)));
                }
                *(ushort4*)&p.fcb[i] = o;
            }
        }
        grid.sync();
        mk_gemm(p.fcb, p.wmo + (size_t)l * E4_ * E_, p.bmo + l * E_, p.pbuf,
                E4_, 384, E_, 192, 6, As, Bs);
        grid.sync();
    }
    for (int u = blk; u < NTOK_; u += 256)
        mk_ln_unit(u, p.h, p.pbuf, 8, p.ids, p.wte, p.wpe, p.lnfg, p.lnfb, p.x, red);
    grid.sync();
    mk_gemm(p.x, p.wcp, p.bcp, p.pbuf, E_, 192, CPD_, 256, 16, As, Bs);
    grid.sync();
    for (int u = blk; u < NVALID_; u += 256)
        mk_zloss_unit(p.pbuf, p.ids, p.lossv, u, zA0, zA1, zB0, zB1, zred);
    grid.sync();
    if (blk == 0) mk_reduce(p.lossv, p.out, red);
}

// ======================================================================

extern "C" void kernel_launch(void* const* d_in, const int* in_sizes, int n_in,
                              void* d_out, int out_size, void* d_ws, size_t ws_size,
                              hipStream_t stream) {
    const int*   ids  = (const int*)d_in[0];
    const float* wte  = (const float*)d_in[1];
    const float* wpe  = (const float*)d_in[2];
    const float* ln1g = (const float*)d_in[3];
    const float* ln1b = (const float*)d_in[4];
    const float* ln2g = (const float*)d_in[5];
    const float* ln2b = (const float*)d_in[6];
    const float* wqkv = (const float*)d_in[7];
    const float* bqkv = (const float*)d_in[8];
    const float* wao  = (const float*)d_in[9];
    const float* bao  = (const float*)d_in[10];
    const float* wfc  = (const float*)d_in[11];
    const float* bfc  = (const float*)d_in[12];
    const float* wmo  = (const float*)d_in[13];
    const float* bmo  = (const float*)d_in[14];
    const float* lnfg = (const float*)d_in[15];
    const float* lnfb = (const float*)d_in[16];
    const float* wcp  = (const float*)d_in[17];
    const float* bcp  = (const float*)d_in[18];

    // workspace layout (bytes) -- ~25 MB, no memsets, no atomics
    char* p = (char*)d_ws;
    float* h    = (float*)p; p += (size_t)NTOK_ * E_ * 4;      // 1.50 MB
    u16*   x    = (u16*)p;   p += (size_t)NTOK_ * E_ * 2;      // 0.75 MB
    u16*   aob  = (u16*)p;   p += (size_t)NTOK_ * E_ * 2;      // 0.75 MB
    u16*   fcb  = (u16*)p;   p += (size_t)NTOK_ * E4_ * 2;     // 3.0 MB
    float* pbuf = (float*)p; p += 4 * QS_ * 4;                 // 18.9 MB split-K partials
    float* lossv = (float*)p; p += 4096;

    MKP mk;
    mk.ids = ids; mk.wte = wte; mk.wpe = wpe;
    mk.ln1g = ln1g; mk.ln1b = ln1b; mk.ln2g = ln2g; mk.ln2b = ln2b;
    mk.wqkv = wqkv; mk.bqkv = bqkv; mk.wao = wao; mk.bao = bao;
    mk.wfc = wfc; mk.bfc = bfc; mk.wmo = wmo; mk.bmo = bmo;
    mk.lnfg = lnfg; mk.lnfb = lnfb; mk.wcp = wcp; mk.bcp = bcp;
    mk.h = h; mk.x = x; mk.aob = aob; mk.fcb = fcb; mk.pbuf = pbuf;
    mk.lossv = lossv; mk.out = (unsigned int*)d_out;

    void* kargs[] = { (void*)&mk };
    hipError_t err = hipLaunchCooperativeKernel((const void*)mega_k,
        dim3(256), dim3(512), kargs, 0, stream);
    if (err == hipSuccess) return;
    (void)hipGetLastError();   // clear; fall back to the proven R8 chain

    for (int l = 0; l < L_; l++) {
        ln_res_k<<<NTOK_, 256, 0, stream>>>(h, pbuf, l ? 8 : -1, ids, wte, wpe,
                                            ln1g + l * E_, ln1b + l * E_, x);
        mgemm_k<<<dim3(E3_ / 128, 4, 4), 512, 0, stream>>>(
            x, wqkv + (size_t)l * E_ * E3_, bqkv + l * E3_, pbuf, E_, 192, E3_);
        fattn_k<<<dim3(4, B_ * NH_), 256, 0, stream>>>(pbuf, aob);
        mgemm_k<<<dim3(E_ / 128, 4, 8), 512, 0, stream>>>(
            aob, wao + (size_t)l * E_ * E_, bao + l * E_, pbuf, E_, 96, E_);
        ln_res_k<<<NTOK_, 256, 0, stream>>>(h, pbuf, 8, ids, wte, wpe,
                                            ln2g + l * E_, ln2b + l * E_, x);
        mgemm_k<<<dim3(E4_ / 128, 4, 2), 512, 0, stream>>>(
            x, wfc + (size_t)l * E_ * E4_, bfc + l * E4_, pbuf, E_, 384, E4_);
        gelu_k<<<(NTOK_ * E4_) / 1024, 256, 0, stream>>>(pbuf, pbuf + FS_, fcb);
        mgemm_k<<<dim3(E_ / 128, 4, 8), 512, 0, stream>>>(
            fcb, wmo + (size_t)l * E4_ * E_, bmo + l * E_, pbuf, E4_, 384, E_);
    }
    ln_res_k<<<NTOK_, 256, 0, stream>>>(h, pbuf, 8, ids, wte, wpe, lnfg, lnfb, x);
    mgemm_k<<<dim3(CPD_ / 128, 4, 4), 512, 0, stream>>>(
        x, wcp, bcp, pbuf, E_, 192, CPD_);
    zloss_k<<<NVALID_, 256, 0, stream>>>(pbuf, ids, lossv);
    reduce_k<<<1, 256, 0, stream>>>(lossv, (unsigned int*)d_out);
}

// Round 10
// 1234.031 us; speedup vs baseline: 3.6654x; 3.6654x over previous
//
#include <hip/hip_runtime.h>

typedef unsigned short u16;
typedef short short8 __attribute__((ext_vector_type(8)));
typedef float f32x4 __attribute__((ext_vector_type(4)));

// Problem constants
constexpr int B_  = 2;
constexpr int T_  = 256;
constexpr int V_  = 512;
constexpr int E_  = 768;
constexpr int L_  = 12;
constexpr int NH_ = 12;
constexpr int HD_ = 64;
constexpr int E3_ = 3 * E_;       // 2304
constexpr int E4_ = 4 * E_;       // 3072
constexpr int CPD_ = 2048;        // H_CP*V*R
constexpr int NTOK_ = B_ * T_;    // 512
constexpr int NVALID_ = B_ * (T_ - 2); // 508
constexpr size_t PS_ = (size_t)NTOK_ * E_;    // ao/mo partial stride (floats)
constexpr size_t QS_ = (size_t)NTOK_ * E3_;   // (sizing only)
constexpr size_t CS_ = (size_t)NTOK_ * CPD_;  // cp partial stride

__device__ __forceinline__ u16 f2b(float f) {  // RNE f32 -> bf16 bits
    union { float f; unsigned int u; } c; c.f = f;
    unsigned int r = (c.u + 0x7FFFu + ((c.u >> 16) & 1u)) >> 16; return (u16)r;
}

// ---------- LayerNorm; np>=1: fuse np split-K partials into residual;
// ---------- np==0: plain LN of h; np==-1: compute h = wte[tok]+wpe (embed) first ----------
__global__ __launch_bounds__(256) void ln_res_k(float* __restrict__ h,
    const float* __restrict__ pb, int np,
    const int* __restrict__ ids, const float* __restrict__ wte,
    const float* __restrict__ wpe,
    const float* __restrict__ g, const float* __restrict__ bta,
    u16* __restrict__ out) {
    int n = blockIdx.x;
    int tid = threadIdx.x;
    size_t off = (size_t)n * E_;
    float v0, v1, v2;
    if (np < 0) {
        int t = n % T_;
        int tok = ids[n];
        size_t wo = (size_t)tok * E_, po = (size_t)t * E_;
        v0 = wte[wo + tid]       + wpe[po + tid];
        v1 = wte[wo + tid + 256] + wpe[po + tid + 256];
        v2 = wte[wo + tid + 512] + wpe[po + tid + 512];
        h[off + tid] = v0; h[off + tid + 256] = v1; h[off + tid + 512] = v2;
    } else {
        v0 = h[off + tid]; v1 = h[off + tid + 256]; v2 = h[off + tid + 512];
        for (int j = 0; j < np; j++) {
            const float* p = pb + (size_t)j * PS_ + off;
            v0 += p[tid]; v1 += p[tid + 256]; v2 += p[tid + 512];
        }
        if (np) { h[off + tid] = v0; h[off + tid + 256] = v1; h[off + tid + 512] = v2; }
    }
    __shared__ float red[256];
    red[tid] = v0 + v1 + v2;
    __syncthreads();
    for (int o = 128; o > 0; o >>= 1) { if (tid < o) red[tid] += red[tid + o]; __syncthreads(); }
    float mean = red[0] * (1.0f / E_);
    __syncthreads();
    float d0 = v0 - mean, d1 = v1 - mean, d2 = v2 - mean;
    red[tid] = d0 * d0 + d1 * d1 + d2 * d2;
    __syncthreads();
    for (int o = 128; o > 0; o >>= 1) { if (tid < o) red[tid] += red[tid + o]; __syncthreads(); }
    float rstd = rsqrtf(red[0] * (1.0f / E_) + 1e-5f);
    u16* y = out + off;
    y[tid]       = f2b(d0 * rstd * g[tid]       + bta[tid]);
    y[tid + 256] = f2b(d1 * rstd * g[tid + 256] + bta[tid + 256]);
    y[tid + 512] = f2b(d2 * rstd * g[tid + 512] + bta[tid + 512]);
}

// -------------------- MFMA GEMM, 128x128 tile, 8 waves (4x2 of 32x64) --------------------
// (exact R8 structure) fp32 split-K partials to outP + kz*NTOK*N; bias on kz==0.
__global__ __launch_bounds__(512) void mgemm_k(const u16* __restrict__ A,
    const float* __restrict__ W, const float* __restrict__ bias,
    float* __restrict__ outP, int K, int KC, int N) {
    __shared__ u16 As[128 * 40];
    __shared__ u16 Bs[128 * 40];
    int tid = threadIdx.x, lane = tid & 63, wid = tid >> 6;
    int ln15 = lane & 15, quad = lane >> 4;
    int col0 = blockIdx.x * 128, row0 = blockIdx.y * 128;
    int kz = blockIdx.z, kbase = kz * KC;
    int ar = tid >> 2, ak = (tid & 3) * 8;
    const u16* Ag = A + (size_t)(row0 + ar) * K + kbase + ak;
    u16* Aw = &As[ar * 40 + ak];
    int bc = tid & 127, kg = (tid >> 7) * 8;
    const float* Wg = W + (size_t)(kbase + kg) * N + col0 + bc;
    u16* Bw = &Bs[bc * 40 + kg];
    int wr = (wid & 3) * 32, wc = (wid >> 2) * 64;

    f32x4 acc[2][4];
#pragma unroll
    for (int mt = 0; mt < 2; mt++)
#pragma unroll
        for (int nt = 0; nt < 4; nt++) acc[mt][nt] = (f32x4){0.f, 0.f, 0.f, 0.f};

    uint4 av = *(const uint4*)Ag;
    float w[8];
#pragma unroll
    for (int i = 0; i < 8; i++) w[i] = Wg[(size_t)i * N];

    for (int k0 = 0; k0 < KC; k0 += 32) {
        uint4 avn = av;
        float wn[8];
#pragma unroll
        for (int i = 0; i < 8; i++) wn[i] = w[i];
        if (k0 + 32 < KC) {
            avn = *(const uint4*)(Ag + k0 + 32);
#pragma unroll
            for (int i = 0; i < 8; i++) wn[i] = Wg[(size_t)(k0 + 32 + i) * N];
        }
        uint4 bv;
        asm("v_cvt_pk_bf16_f32 %0, %1, %2" : "=v"(bv.x) : "v"(w[0]), "v"(w[1]));
        asm("v_cvt_pk_bf16_f32 %0, %1, %2" : "=v"(bv.y) : "v"(w[2]), "v"(w[3]));
        asm("v_cvt_pk_bf16_f32 %0, %1, %2" : "=v"(bv.z) : "v"(w[4]), "v"(w[5]));
        asm("v_cvt_pk_bf16_f32 %0, %1, %2" : "=v"(bv.w) : "v"(w[6]), "v"(w[7]));
        __syncthreads();
        *(uint4*)Aw = av;
        *(uint4*)Bw = bv;
        __syncthreads();
        short8 af[2], bf[4];
#pragma unroll
        for (int mt = 0; mt < 2; mt++)
            af[mt] = *(const short8*)&As[(wr + mt * 16 + ln15) * 40 + quad * 8];
#pragma unroll
        for (int nt = 0; nt < 4; nt++)
            bf[nt] = *(const short8*)&Bs[(wc + nt * 16 + ln15) * 40 + quad * 8];
#pragma unroll
        for (int mt = 0; mt < 2; mt++)
#pragma unroll
            for (int nt = 0; nt < 4; nt++)
                acc[mt][nt] = __builtin_amdgcn_mfma_f32_16x16x32_bf16(
                    af[mt], bf[nt], acc[mt][nt], 0, 0, 0);
        av = avn;
#pragma unroll
        for (int i = 0; i < 8; i++) w[i] = wn[i];
    }
    // C/D layout: col=lane&15, row=quad*4+reg (m89-verified)
    float* dst = outP + (size_t)kz * NTOK_ * N;
#pragma unroll
    for (int mt = 0; mt < 2; mt++) {
#pragma unroll
        for (int nt = 0; nt < 4; nt++) {
            int c = col0 + wc + nt * 16 + ln15;
            float bb = (kz == 0) ? bias[c] : 0.f;
#pragma unroll
            for (int r = 0; r < 4; r++) {
                int rw = row0 + wr + mt * 16 + quad * 4 + r;
                dst[(size_t)rw * N + c] = acc[mt][nt][r] + bb;
            }
        }
    }
}

// -------------------- MFMA GEMM, 128x64 tile, 8 waves (4x2 of 32x32), KS=1 ---------------
// (R2-proven geometry + R4-style register prefetch; bf16 epilogues, no partials)
// mode 3: out = bf16(acc + bias)          (qkv)
// mode 1: out = bf16(gelu(acc + bias))    (fc)
__global__ __launch_bounds__(512) void mgemm64_k(const u16* __restrict__ A,
    const float* __restrict__ W, const float* __restrict__ bias,
    u16* __restrict__ outB, int K, int N, int mode) {
    __shared__ u16 As[128 * 40];
    __shared__ u16 Bs[64 * 40];
    int tid = threadIdx.x, lane = tid & 63, wid = tid >> 6;
    int ln15 = lane & 15, quad = lane >> 4;
    int col0 = blockIdx.x * 64, row0 = blockIdx.y * 128;
    int ar = tid >> 2, ak = (tid & 3) * 8;    // A: 128 rows x 32 k, uint4/thread
    const u16* Ag = A + (size_t)(row0 + ar) * K + ak;
    u16* Aw = &As[ar * 40 + ak];
    int bc = tid & 63, kg = (tid >> 6) * 4;   // B: col bc, 4 k-rows per wave-group
    const float* Wg = W + (size_t)kg * N + col0 + bc;
    u16* Bw = &Bs[bc * 40 + kg];
    int wr = (wid & 3) * 32, wc = (wid >> 2) * 32;

    f32x4 acc[2][2];
    acc[0][0] = (f32x4){0.f,0.f,0.f,0.f}; acc[0][1] = (f32x4){0.f,0.f,0.f,0.f};
    acc[1][0] = (f32x4){0.f,0.f,0.f,0.f}; acc[1][1] = (f32x4){0.f,0.f,0.f,0.f};

    uint4 av = *(const uint4*)Ag;
    float w[4];
#pragma unroll
    for (int i = 0; i < 4; i++) w[i] = Wg[(size_t)i * N];

    for (int k0 = 0; k0 < K; k0 += 32) {
        uint4 avn = av;
        float wn[4];
#pragma unroll
        for (int i = 0; i < 4; i++) wn[i] = w[i];
        if (k0 + 32 < K) {
            avn = *(const uint4*)(Ag + k0 + 32);
#pragma unroll
            for (int i = 0; i < 4; i++) wn[i] = Wg[(size_t)(k0 + 32 + i) * N];
        }
        uint2 bv;
        asm("v_cvt_pk_bf16_f32 %0, %1, %2" : "=v"(bv.x) : "v"(w[0]), "v"(w[1]));
        asm("v_cvt_pk_bf16_f32 %0, %1, %2" : "=v"(bv.y) : "v"(w[2]), "v"(w[3]));
        __syncthreads();
        *(uint4*)Aw = av;
        *(uint2*)Bw = bv;
        __syncthreads();
        short8 af[2], bf[2];
#pragma unroll
        for (int mt = 0; mt < 2; mt++)
            af[mt] = *(const short8*)&As[(wr + mt * 16 + ln15) * 40 + quad * 8];
#pragma unroll
        for (int nt = 0; nt < 2; nt++)
            bf[nt] = *(const short8*)&Bs[(wc + nt * 16 + ln15) * 40 + quad * 8];
#pragma unroll
        for (int mt = 0; mt < 2; mt++)
#pragma unroll
            for (int nt = 0; nt < 2; nt++)
                acc[mt][nt] = __builtin_amdgcn_mfma_f32_16x16x32_bf16(
                    af[mt], bf[nt], acc[mt][nt], 0, 0, 0);
        av = avn;
#pragma unroll
        for (int i = 0; i < 4; i++) w[i] = wn[i];
    }
    // C/D layout: col=lane&15, row=quad*4+reg (m89-verified)
#pragma unroll
    for (int mt = 0; mt < 2; mt++) {
#pragma unroll
        for (int nt = 0; nt < 2; nt++) {
            int c = col0 + wc + nt * 16 + ln15;
            float bb = bias[c];
            if (mode == 3) {
#pragma unroll
                for (int r = 0; r < 4; r++) {
                    int rw = row0 + wr + mt * 16 + quad * 4 + r;
                    outB[(size_t)rw * N + c] = f2b(acc[mt][nt][r] + bb);
                }
            } else {
#pragma unroll
                for (int r = 0; r < 4; r++) {
                    int rw = row0 + wr + mt * 16 + quad * 4 + r;
                    float u = acc[mt][nt][r] + bb;
                    float inner = 0.7978845608028654f * (u + 0.044715f * u * u * u);
                    float v = 0.5f * u * (1.0f + tanhf(inner));
                    outB[(size_t)rw * N + c] = f2b(v);
                }
            }
        }
    }
}

// -------------------- MFMA flash attention (bf16 qkv in; exact R2 version) ---------------
// grid (4 q-tiles of 64, B*NH), 256 threads (4 waves).
constexpr int KSTR_ = 72;   // K LDS row stride (elems)
constexpr int PSTR_ = 264;  // P/Vt LDS row stride
__global__ __launch_bounds__(256) void fattn_k(const u16* __restrict__ qkv,
    u16* __restrict__ o) {
    __shared__ u16 Ks[256 * KSTR_];   // 36864 B
    __shared__ u16 Vt[64 * PSTR_];    // 33792 B
    __shared__ u16 Ps[64 * PSTR_];    // 33792 B
    int qt = blockIdx.x;
    int bh = blockIdx.y;
    int hh = bh % NH_, b = bh / NH_;
    int tid = threadIdx.x, lane = tid & 63, wid = tid >> 6;
    int ln15 = lane & 15, quad = lane >> 4;

    // ---- stage K, V^T (bf16 passthrough) ----
    int sr = tid >> 4, sd = (tid & 15) * 4;
#pragma unroll
    for (int pass = 0; pass < 16; pass++) {
        int rr = sr + pass * 16;
        uint2 kv = *(const uint2*)&qkv[(size_t)(b * T_ + rr) * E3_ + E_ + hh * HD_ + sd];
        *(uint2*)&Ks[rr * KSTR_ + sd] = kv;
        ushort4 vv = *(const ushort4*)&qkv[(size_t)(b * T_ + rr) * E3_ + 2 * E_ + hh * HD_ + sd];
        Vt[(sd + 0) * PSTR_ + rr] = vv.x;
        Vt[(sd + 1) * PSTR_ + rr] = vv.y;
        Vt[(sd + 2) * PSTR_ + rr] = vv.z;
        Vt[(sd + 3) * PSTR_ + rr] = vv.w;
    }

    // ---- Q fragments straight from global ----
    const u16* Qg = qkv + (size_t)(b * T_ + qt * 64 + wid * 16 + ln15) * E3_ + hh * HD_;
    short8 qf[2];
#pragma unroll
    for (int ks = 0; ks < 2; ks++)
        qf[ks] = *(const short8*)&Qg[ks * 32 + quad * 8];

    __syncthreads();

    // ---- S = Q.K^T : wave computes 16 q-rows x 256 cols ----
    f32x4 s[16];
#pragma unroll
    for (int nt = 0; nt < 16; nt++) s[nt] = (f32x4){0.f, 0.f, 0.f, 0.f};
#pragma unroll
    for (int ks = 0; ks < 2; ks++) {
#pragma unroll
        for (int nt = 0; nt < 16; nt++) {
            short8 kf = *(const short8*)&Ks[(nt * 16 + ln15) * KSTR_ + ks * 32 + quad * 8];
            s[nt] = __builtin_amdgcn_mfma_f32_16x16x32_bf16(qf[ks], kf, s[nt], 0, 0, 0);
        }
    }

    // ---- masked softmax, in-register per row ----
#pragma unroll
    for (int r = 0; r < 4; r++) {
        int q = qt * 64 + wid * 16 + quad * 4 + r;
        float m = -1e30f;
#pragma unroll
        for (int nt = 0; nt < 16; nt++) {
            int j = nt * 16 + ln15;
            float sv = (j <= q) ? s[nt][r] * 0.125f : -1e9f;
            s[nt][r] = sv;
            m = fmaxf(m, sv);
        }
        m = fmaxf(m, __shfl_xor(m, 1));
        m = fmaxf(m, __shfl_xor(m, 2));
        m = fmaxf(m, __shfl_xor(m, 4));
        m = fmaxf(m, __shfl_xor(m, 8));
        float sum = 0.f;
#pragma unroll
        for (int nt = 0; nt < 16; nt++) {
            float p = __expf(s[nt][r] - m);
            s[nt][r] = p;
            sum += p;
        }
        sum += __shfl_xor(sum, 1);
        sum += __shfl_xor(sum, 2);
        sum += __shfl_xor(sum, 4);
        sum += __shfl_xor(sum, 8);
        float inv = 1.0f / sum;
#pragma unroll
        for (int nt = 0; nt < 16; nt++) s[nt][r] *= inv;
    }

    // ---- P -> LDS (bf16, A-frag layout rows) ----
#pragma unroll
    for (int nt = 0; nt < 16; nt++)
#pragma unroll
        for (int r = 0; r < 4; r++)
            Ps[(wid * 16 + quad * 4 + r) * PSTR_ + nt * 16 + ln15] = f2b(s[nt][r]);

    __syncthreads();

    // ---- O = P.V : 16 rows x 64 cols per wave ----
    f32x4 oacc[4];
#pragma unroll
    for (int dt = 0; dt < 4; dt++) oacc[dt] = (f32x4){0.f, 0.f, 0.f, 0.f};
#pragma unroll
    for (int ks = 0; ks < 8; ks++) {
        short8 pf = *(const short8*)&Ps[(wid * 16 + ln15) * PSTR_ + ks * 32 + quad * 8];
#pragma unroll
        for (int dt = 0; dt < 4; dt++) {
            short8 vf = *(const short8*)&Vt[(dt * 16 + ln15) * PSTR_ + ks * 32 + quad * 8];
            oacc[dt] = __builtin_amdgcn_mfma_f32_16x16x32_bf16(pf, vf, oacc[dt], 0, 0, 0);
        }
    }

    // ---- store O bf16 ----
#pragma unroll
    for (int dt = 0; dt < 4; dt++) {
#pragma unroll
        for (int r = 0; r < 4; r++) {
            int q = qt * 64 + wid * 16 + quad * 4 + r;
            o[(size_t)(b * T_ + q) * E_ + hh * HD_ + dt * 16 + ln15] = f2b(oacc[dt][r]);
        }
    }
}

// -------------------- Z / per-token loss (sums 4 cp partials) --------------------
__global__ __launch_bounds__(256) void zloss_k(const float* __restrict__ cp,
    const int* __restrict__ ids, float* __restrict__ lossv) {
    int n = blockIdx.x;
    int b = n / (T_ - 2), t = n % (T_ - 2);
    int nf = b * T_ + t;
    size_t base = (size_t)nf * CPD_;
    __shared__ float A0[V_], A1[V_], B0[V_], B1[V_];
    __shared__ float red[256];
    int tid = threadIdx.x;
    for (int v = tid; v < V_; v += 256) {
        float a0 = 0.f, a1 = 0.f, b0 = 0.f, b1 = 0.f;
#pragma unroll
        for (int pi = 0; pi < 4; pi++) {
            const float* ap = cp + pi * CS_ + base;
            float2 av = *(const float2*)&ap[2 * v];
            float2 bv = *(const float2*)&ap[1024 + 2 * v];
            a0 += av.x; a1 += av.y; b0 += bv.x; b1 += bv.y;
        }
        A0[v] = a0; A1[v] = a1; B0[v] = b0; B1[v] = b1;
    }
    __syncthreads();
    float acc = 0.f;
    for (int j = tid; j < V_; j += 256) {
        float b0 = B0[j], b1 = B1[j];
        for (int i = 0; i < V_; i++)
            acc += __expf(A0[i] * b0 + A1[i] * b1);
    }
    red[tid] = acc; __syncthreads();
    for (int off = 128; off > 0; off >>= 1) { if (tid < off) red[tid] += red[tid + off]; __syncthreads(); }
    if (tid == 0) {
        int t0 = ids[b * T_ + t + 1];
        int t1 = ids[b * T_ + t + 2];
        float score = A0[t0] * B0[t1] + A1[t0] * B1[t1];
        lossv[n] = logf(red[0]) - score;
    }
}

// -------------------- final mean; dual-encoded scalar --------------------
__global__ __launch_bounds__(256) void reduce_k(const float* __restrict__ lossv,
    unsigned int* __restrict__ out) {
    __shared__ float red[256];
    int tid = threadIdx.x;
    float s = 0.f;
    for (int i = tid; i < NVALID_; i += 256) s += lossv[i];
    red[tid] = s; __syncthreads();
    for (int off = 128; off > 0; off >>= 1) { if (tid < off) red[tid] += red[tid + off]; __syncthreads(); }
    if (tid == 0) {
        float loss = red[0] / (float)NVALID_;
        union { float f; unsigned int u; } cv; cv.f = loss;
        unsigned int b = (cv.u + 0x7FFFu + ((cv.u >> 16) & 1u)) >> 16;
        out[0] = (b << 16) | b;
    }
}

extern "C" void kernel_launch(void* const* d_in, const int* in_sizes, int n_in,
                              void* d_out, int out_size, void* d_ws, size_t ws_size,
                              hipStream_t stream) {
    const int*   ids  = (const int*)d_in[0];
    const float* wte  = (const float*)d_in[1];
    const float* wpe  = (const float*)d_in[2];
    const float* ln1g = (const float*)d_in[3];
    const float* ln1b = (const float*)d_in[4];
    const float* ln2g = (const float*)d_in[5];
    const float* ln2b = (const float*)d_in[6];
    const float* wqkv = (const float*)d_in[7];
    const float* bqkv = (const float*)d_in[8];
    const float* wao  = (const float*)d_in[9];
    const float* bao  = (const float*)d_in[10];
    const float* wfc  = (const float*)d_in[11];
    const float* bfc  = (const float*)d_in[12];
    const float* wmo  = (const float*)d_in[13];
    const float* bmo  = (const float*)d_in[14];
    const float* lnfg = (const float*)d_in[15];
    const float* lnfb = (const float*)d_in[16];
    const float* wcp  = (const float*)d_in[17];
    const float* bcp  = (const float*)d_in[18];

    // workspace layout (bytes) -- ~27 MB, no memsets, no atomics
    char* p = (char*)d_ws;
    float* h    = (float*)p; p += (size_t)NTOK_ * E_ * 4;      // 1.50 MB
    u16*   x    = (u16*)p;   p += (size_t)NTOK_ * E_ * 2;      // 0.75 MB
    u16*   aob  = (u16*)p;   p += (size_t)NTOK_ * E_ * 2;      // 0.75 MB
    u16*   fcb  = (u16*)p;   p += (size_t)NTOK_ * E4_ * 2;     // 3.0 MB
    u16*   qkvB = (u16*)p;   p += (size_t)NTOK_ * E3_ * 2;     // 2.25 MB
    float* pbuf = (float*)p; p += 4 * QS_ * 4;                 // 18.9 MB (ao/mo 8xPS_, cp 4xCS_)
    float* lossv = (float*)p; p += 4096;

    for (int l = 0; l < L_; l++) {
        // ln1: l==0 computes the embedding in-place (np=-1); else fuses 8 mo partials
        ln_res_k<<<NTOK_, 256, 0, stream>>>(h, pbuf, l ? 8 : -1, ids, wte, wpe,
                                            ln1g + l * E_, ln1b + l * E_, x);
        mgemm64_k<<<dim3(E3_ / 64, 4), 512, 0, stream>>>(           // qkv: KS=1, bf16 out
            x, wqkv + (size_t)l * E_ * E3_, bqkv + l * E3_, qkvB, E_, E3_, 3);
        fattn_k<<<dim3(4, B_ * NH_), 256, 0, stream>>>(qkvB, aob);
        mgemm_k<<<dim3(E_ / 128, 4, 8), 512, 0, stream>>>(          // ao: KS=8, KC=96
            aob, wao + (size_t)l * E_ * E_, bao + l * E_, pbuf, E_, 96, E_);
        ln_res_k<<<NTOK_, 256, 0, stream>>>(h, pbuf, 8, ids, wte, wpe,
                                            ln2g + l * E_, ln2b + l * E_, x);
        mgemm64_k<<<dim3(E4_ / 64, 4), 512, 0, stream>>>(           // fc: KS=1, gelu bf16 out
            x, wfc + (size_t)l * E_ * E4_, bfc + l * E4_, fcb, E_, E4_, 1);
        mgemm_k<<<dim3(E_ / 128, 4, 8), 512, 0, stream>>>(          // mo: KS=8, KC=384
            fcb, wmo + (size_t)l * E4_ * E_, bmo + l * E_, pbuf, E4_, 384, E_);
    }
    ln_res_k<<<NTOK_, 256, 0, stream>>>(h, pbuf, 8, ids, wte, wpe, lnfg, lnfb, x);
    mgemm_k<<<dim3(CPD_ / 128, 4, 4), 512, 0, stream>>>(            // cp: KS=4, KC=192
        x, wcp, bcp, pbuf, E_, 192, CPD_);
    zloss_k<<<NVALID_, 256, 0, stream>>>(pbuf, ids, lossv);
    reduce_k<<<1, 256, 0, stream>>>(lossv, (unsigned int*)d_out);
}